// Round 9
// baseline (55.069 us; speedup 1.0000x reference)
//
#include <hip/hip_runtime.h>
#include <math.h>

#define NOBJ  32
#define NANCH 16384
#define NTOT  131072      // 8 * 16384
#define NBLK  128         // dl_fused blocks (1024 threads each -> 1 anchor/thread)
#define NREP  8           // global histogram replicas
#define MARK  0xFFFFFFFFu

// ---- ws word layout ----
#define OFF_SLOTS 64                 // 128 blocks * 8 words (np, nn, box, pos, wsum)
#define OFF_H1C   1088               // 8 replicas * 4096 cnt (top-12-bit)
#define OFF_H2C   33856              // 8 replicas * 4096 cnt (mid-12-bit)
#define OFF_H3C   66624              // 8 replicas * 256 cnt (low-8-bit)
#define OFF_FLAG  68672              // 128 blocks * 16-word stride (barrier flags)
#define OFF_FSL   70720              // 128 f32 partial sums
#define OFF_ZERO_BEG  OFF_H1C
#define OFF_ZERO_WORDS 69632         // H1C..FLAG inclusive
// total = 70848 words ~= 283 KB (ws proven far larger)

__device__ __forceinline__ float smooth_l1f(float d) {
    float ad = fabsf(d);
    return ad < 1.0f ? 0.5f * ad * ad : ad - 0.5f;
}

// kernel 1: zero hist replicas + barrier flags (fresh every call/replay)
__global__ __launch_bounds__(256) void dl_zero(unsigned int* __restrict__ ws)
{
    int i = blockIdx.x * 256 + threadIdx.x;
    for (int w = i; w < OFF_ZERO_WORDS; w += 128 * 256) ws[OFF_ZERO_BEG + w] = 0u;
}

// flag-broadcast grid barrier: no atomic RMW, each block owns one flag line
__device__ __forceinline__ void gbar(unsigned* ws, unsigned phase) {
    __syncthreads();
    if (threadIdx.x < 64) {
        if (threadIdx.x == 0) {
            __threadfence();
            __hip_atomic_store(ws + OFF_FLAG + blockIdx.x * 16, phase,
                               __ATOMIC_RELEASE, __HIP_MEMORY_SCOPE_AGENT);
        }
        bool ok;
        do {
            unsigned v0 = __hip_atomic_load(ws + OFF_FLAG + threadIdx.x * 16,
                                            __ATOMIC_ACQUIRE, __HIP_MEMORY_SCOPE_AGENT);
            unsigned v1 = __hip_atomic_load(ws + OFF_FLAG + (64 + threadIdx.x) * 16,
                                            __ATOMIC_ACQUIRE, __HIP_MEMORY_SCOPE_AGENT);
            ok = __all(v0 >= phase && v1 >= phase);
            if (!ok) __builtin_amdgcn_s_sleep(1);
        } while (!ok);
    }
    __syncthreads();
}

// kernel 2: everything — per-anchor compute + 3-level radix select, 3 barriers
__global__ __launch_bounds__(1024) void dl_fused(
    const float* __restrict__ pred_boxes,
    const float* __restrict__ pred_classes,
    const float* __restrict__ true_boxes,
    const int*   __restrict__ true_classes,
    const float* __restrict__ anchors,
    unsigned int* __restrict__ ws,
    float* __restrict__ out)
{
    __shared__ unsigned hrep[4][4096];   // 64 KB replicated count hist
    __shared__ float s_tb[NOBJ * 4];
    __shared__ int   s_tc[NOBJ];
    __shared__ int   wtot[16];
    __shared__ int   s_wi[16][2];
    __shared__ float s_wf[16][3];
    __shared__ int   sh[4];

    const int t = threadIdx.x, wave = t >> 6, lane = t & 63, rep = wave >> 2;
    const bool b0 = (blockIdx.x == 0);
    unsigned* hflat = &hrep[0][0];

    const int idx = blockIdx.x * 1024 + t;   // 16 blocks per image; no straddling
    const int b = idx >> 14;
    const int a = idx & (NANCH - 1);
    if (t < NOBJ * 4) s_tb[t] = true_boxes[b * NOBJ * 4 + t];
    if (t < NOBJ)     s_tc[t] = true_classes[b * NOBJ + t];
    for (int i = t; i < 16384; i += 1024) hflat[i] = 0u;
    __syncthreads();

    // ---- phase 0: per-anchor compute (proven R2-R8 math) ----
    float4 anc = reinterpret_cast<const float4*>(anchors)[a];   // (cx, cy, w, h)
    float ax1 = anc.x - anc.z * 0.5f;
    float ay1 = anc.y - anc.w * 0.5f;
    float ax2 = anc.x + anc.z * 0.5f;
    float ay2 = anc.y + anc.w * 0.5f;
    float area_a = (ax2 - ax1) * (ay2 - ay1);

    float ov[NOBJ];
    float best = -3.402823466e38f;
#pragma unroll
    for (int o = 0; o < NOBJ; ++o) {
        float v;
        if (s_tc[o] < 0) {
            v = -1.0f;   // reference masks padded slots' overlap to -1
        } else {
            float bx1 = s_tb[o * 4 + 0], by1 = s_tb[o * 4 + 1];
            float bx2 = s_tb[o * 4 + 2], by2 = s_tb[o * 4 + 3];
            float ltx = fmaxf(ax1, bx1), lty = fmaxf(ay1, by1);
            float rbx = fminf(ax2, bx2), rby = fminf(ay2, by2);
            float w = fmaxf(rbx - ltx, 0.0f), h = fmaxf(rby - lty, 0.0f);
            float inter = w * h;
            float area_b = (bx2 - bx1) * (by2 - by1);
            v = inter / (area_a + area_b - inter);
        }
        ov[o] = v;
        best = fmaxf(best, v);
    }

    float2 pc = reinterpret_cast<const float2*>(pred_classes)[idx];
    float mx = fmaxf(pc.x, pc.y);
    float lse = mx + logf(expf(pc.x - mx) + expf(pc.y - mx));
    float l0 = pc.x - lse;
    float l1 = pc.y - lse;

    unsigned bits = MARK;   // negative-candidate bit pattern (nce > 0 orders as uint)
    int isneg = 0;
    if (best < 0.5f) { bits = __float_as_uint(-l0); isneg = 1; }

    float4 pb = reinterpret_cast<const float4*>(pred_boxes)[idx];
    int npos = 0; float boxs = 0.f, poss = 0.f, wsum = 0.f;
#pragma unroll
    for (int o = 0; o < NOBJ; ++o) {
        float v = ov[o];
        if (fabsf(best - v) < 1e-6f && v > 0.5f) {
            ++npos;
            float bx1 = s_tb[o * 4 + 0], by1 = s_tb[o * 4 + 1];
            float bx2 = s_tb[o * 4 + 2], by2 = s_tb[o * 4 + 3];
            float gcx = ((bx1 + bx2) * 0.5f - anc.x) / (0.1f * anc.z);
            float gcy = ((by1 + by2) * 0.5f - anc.y) / (0.1f * anc.w);
            float gw  = logf((bx2 - bx1) / anc.z) / 0.2f;
            float gh  = logf((by2 - by1) / anc.w) / 0.2f;
            boxs += smooth_l1f(pb.x - gcx) + smooth_l1f(pb.y - gcy)
                  + smooth_l1f(pb.z - gw)  + smooth_l1f(pb.w - gh);
            int c = s_tc[o];
            float w = (c == 1) ? 4.0f : 1.0f;
            poss += w * ((c == 1) ? -l1 : -l0);
            wsum += w;
        }
    }

    // P1 LDS histogram (top 12 bits) — thread-local data, so pre-barrier
    if (bits != MARK) atomicAdd(&hrep[rep][bits >> 20], 1u);

    // block reduce the 5 stats
    int ip = npos, ng = isneg;
    float fb = boxs, fp2 = poss, fw2 = wsum;
#pragma unroll
    for (int o = 32; o; o >>= 1) {
        ip += __shfl_down(ip, o); ng += __shfl_down(ng, o);
        fb += __shfl_down(fb, o); fp2 += __shfl_down(fp2, o); fw2 += __shfl_down(fw2, o);
    }
    if (lane == 0) {
        s_wi[wave][0] = ip; s_wi[wave][1] = ng;
        s_wf[wave][0] = fb; s_wf[wave][1] = fp2; s_wf[wave][2] = fw2;
    }
    __syncthreads();   // covers LDS hist atomics + s_w* stores
    // merge P1 hist to global replica
    {
        unsigned* g = ws + OFF_H1C + (blockIdx.x & (NREP - 1)) * 4096;
#pragma unroll
        for (int i = 0; i < 4; ++i) {
            int bkt = t * 4 + i;
            unsigned c = hrep[0][bkt] + hrep[1][bkt] + hrep[2][bkt] + hrep[3][bkt];
            if (c) atomicAdd(g + bkt, c);
        }
    }
    if (t == 0) {
        int tp = 0, tn = 0; float t2 = 0.f, t3 = 0.f, t4 = 0.f;
        for (int w = 0; w < 16; ++w) {
            tp += s_wi[w][0]; tn += s_wi[w][1];
            t2 += s_wf[w][0]; t3 += s_wf[w][1]; t4 += s_wf[w][2];
        }
        unsigned* sl = ws + OFF_SLOTS + blockIdx.x * 8;
        sl[0] = (unsigned)tp; sl[1] = (unsigned)tn;
        sl[2] = __float_as_uint(t2); sl[3] = __float_as_uint(t3); sl[4] = __float_as_uint(t4);
    }
    gbar(ws, 1u);   // B1: phase0 + P1 merged grid-wide

    // ---- slots reduce (all blocks redundantly -> grid-uniform decisions) ----
    int np = 0, nn = 0; float fbx = 0.f, fp = 0.f, fw = 0.f;
    if (t < NBLK) {
        const unsigned* sl = ws + OFF_SLOTS + t * 8;
        np = (int)sl[0]; nn = (int)sl[1];
        fbx = __uint_as_float(sl[2]); fp = __uint_as_float(sl[3]); fw = __uint_as_float(sl[4]);
    }
#pragma unroll
    for (int o = 32; o; o >>= 1) {
        np += __shfl_down(np, o); nn += __shfl_down(nn, o);
        fbx += __shfl_down(fbx, o); fp += __shfl_down(fp, o); fw += __shfl_down(fw, o);
    }
    if (lane == 0 && wave < 2) {
        s_wi[wave][0] = np; s_wi[wave][1] = nn;
        s_wf[wave][0] = fbx; s_wf[wave][1] = fp; s_wf[wave][2] = fw;
    }
    __syncthreads();
    np = s_wi[0][0] + s_wi[1][0]; nn = s_wi[0][1] + s_wi[1][1];
    fbx = s_wf[0][0] + s_wf[1][0]; fp = s_wf[0][1] + s_wf[1][1]; fw = s_wf[0][2] + s_wf[1][2];

    long long k10 = 10LL * (long long)np;
    int k = (int)((k10 < (long long)nn) ? k10 : (long long)nn);
    float denom = (float)(np > 1 ? np : 1);
    float box_loss = fbx / denom;

    if (k == 0) {   // grid-uniform; flags re-zeroed next call, safe to exit
        if (b0 && t == 0) {
            float cls = 10.0f * fp / fmaxf(fw, 1e-6f) / denom;
            out[0] = box_loss; out[1] = cls; out[2] = box_loss + cls;
        }
        return;
    }

    // parallel cutoff select over 4096 merged buckets (identical in all blocks)
    auto sel12 = [&](int off, int target) {
        unsigned c4[4] = {0u, 0u, 0u, 0u};
#pragma unroll
        for (int r = 0; r < NREP; ++r) {
            uint4 u = reinterpret_cast<const uint4*>(ws + off + r * 4096)[t];
            c4[0] += u.x; c4[1] += u.y; c4[2] += u.z; c4[3] += u.w;
        }
        int cc = (int)(c4[0] + c4[1] + c4[2] + c4[3]);
        int v = cc;
#pragma unroll
        for (int o = 1; o < 64; o <<= 1) {       // wave-local suffix-inclusive
            int u2 = __shfl_down(v, o);
            if (lane + o < 64) v += u2;
        }
        if (lane == 0) wtot[wave] = v;
        __syncthreads();
        int S = v;
        for (int w = wave + 1; w < 16; ++w) S += wtot[w];
        if (S >= target && S - cc < target) {     // exactly one thread
            int cum = S - cc;
            for (int bq = 3; bq >= 0; --bq) {
                int cb = (int)c4[bq];
                if (cum + cb >= target) { sh[0] = t * 4 + bq; sh[1] = target - cum; break; }
                cum += cb;
            }
        }
        __syncthreads();
    };

    // ---- sel1 -> always continue to P2 (no early exit; P3 handles full buckets) ----
    sel12(OFF_H1C, k);
    int b1 = sh[0], r1 = sh[1];

    // ---- P2: mid-12-bit hist within bucket b1 ----
    for (int i = t; i < 16384; i += 1024) hflat[i] = 0u;
    __syncthreads();
    if ((int)(bits >> 20) == b1) atomicAdd(&hrep[rep][(bits >> 8) & 0xFFFu], 1u);
    __syncthreads();
    {
        unsigned* g = ws + OFF_H2C + (blockIdx.x & (NREP - 1)) * 4096;
#pragma unroll
        for (int i = 0; i < 4; ++i) {
            int bkt = t * 4 + i;
            unsigned c = hrep[0][bkt] + hrep[1][bkt] + hrep[2][bkt] + hrep[3][bkt];
            if (c) atomicAdd(g + bkt, c);
        }
    }
    gbar(ws, 2u);   // B2

    sel12(OFF_H2C, r1);
    int b2 = sh[0], r2 = sh[1];
    unsigned pfx = ((unsigned)b1 << 12) | (unsigned)b2;

    // ---- P3: low-8-bit count hist within pfx + per-block partial sum ----
    if (t < 1024) hrep[t >> 8][t & 255] = 0u;   // zero 4x256
    __syncthreads();
    if ((bits >> 8) == pfx) atomicAdd(&hrep[rep][bits & 0xFFu], 1u);
    // partial: candidates certainly selected regardless of low-8 cut
    float loc = (bits != MARK && (bits >> 8) > pfx) ? __uint_as_float(bits) : 0.f;
#pragma unroll
    for (int o = 32; o; o >>= 1) loc += __shfl_down(loc, o);
    if (lane == 0) s_wf[wave][0] = loc;
    __syncthreads();
    if (t < 256) {
        unsigned c = hrep[0][t] + hrep[1][t] + hrep[2][t] + hrep[3][t];
        if (c) atomicAdd(ws + OFF_H3C + (blockIdx.x & (NREP - 1)) * 256 + t, c);
    }
    if (t == 0) {
        float s = 0.f;
        for (int w = 0; w < 16; ++w) s += s_wf[w][0];
        ((float*)ws)[OFF_FSL + blockIdx.x] = s;
    }
    gbar(ws, 3u);   // B3

    // ---- finalize: block 0 only; tail from counts (values exact per bucket) ----
    if (!b0) return;
    int c = 0;
    if (t < 256)
        for (int r = 0; r < NREP; ++r) c += (int)ws[OFF_H3C + r * 256 + t];
    int v = c;
#pragma unroll
    for (int o = 1; o < 64; o <<= 1) {
        int u2 = __shfl_down(v, o);
        if (lane + o < 64) v += u2;
    }
    if (lane == 0) wtot[wave] = v;
    __syncthreads();
    int S = v;
    for (int w = wave + 1; w < 16; ++w) S += wtot[w];
    if (t < 256 && S >= r2 && S - c < r2) { sh[0] = t; sh[1] = r2 - (S - c); }
    __syncthreads();
    int cut = sh[0], rrem = sh[1];

    // combined reduce: low-8 tail terms + FSL partials (fixed-order -> deterministic)
    float term = 0.f;
    if (t < 256) {
        float vv = __uint_as_float((pfx << 8) | (unsigned)t);
        if (t > cut) term = (float)c * vv;
        else if (t == cut) term = (float)rrem * vv;
    }
    if (t < NBLK) term += ((const float*)ws)[OFF_FSL + t];
#pragma unroll
    for (int o = 32; o; o >>= 1) term += __shfl_down(term, o);
    if (lane == 0) s_wf[wave][0] = term;
    __syncthreads();
    if (t == 0) {
        float sneg = 0.f;
        for (int w = 0; w < 16; ++w) sneg += s_wf[w][0];
        float cls = 10.0f * (fp + sneg) / fmaxf(fw + (float)k, 1e-6f) / denom;
        out[0] = box_loss; out[1] = cls; out[2] = box_loss + cls;
    }
}

extern "C" void kernel_launch(void* const* d_in, const int* in_sizes, int n_in,
                              void* d_out, int out_size, void* d_ws, size_t ws_size,
                              hipStream_t stream)
{
    const float* pred_boxes   = (const float*)d_in[0];
    const float* pred_classes = (const float*)d_in[1];
    const float* true_boxes   = (const float*)d_in[2];
    const int*   true_classes = (const int*)d_in[3];
    const float* anchors      = (const float*)d_in[4];
    unsigned int* ws = (unsigned int*)d_ws;

    dl_zero<<<128, 256, 0, stream>>>(ws);
    dl_fused<<<NBLK, 1024, 0, stream>>>(pred_boxes, pred_classes, true_boxes,
                                        true_classes, anchors, ws, (float*)d_out);
}

// Round 10
// 28.751 us; speedup vs baseline: 1.9154x; 1.9154x over previous
//
#include <hip/hip_runtime.h>
#include <math.h>

#define NOBJ  32
#define NANCH 16384
#define NTOT  131072      // 8 * 16384
#define MBLK  256         // dl_main blocks (512 threads, 1 anchor/thread)
#define NREP  16          // global histogram replicas

// ---- ws word layout ----
#define OFF_SLOTS 64                 // 256 blocks * 8 words (np, nn, box, pos, wsum)
#define OFF_HC    2112               // NREP * (cnt[4096] + f32 sum[4096]) = 131072 words
#define HWORDS    (NREP * 8192)
// total = OFF_HC + HWORDS = 133184 words ~= 533 KB (ws proven far larger)

__device__ __forceinline__ float smooth_l1f(float d) {
    float ad = fabsf(d);
    return ad < 1.0f ? 0.5f * ad * ad : ad - 0.5f;
}

// kernel 1: zero the histogram replicas (128 blocks * 256 * uint4 = 131072 words)
__global__ __launch_bounds__(256) void dl_zero(unsigned int* __restrict__ ws)
{
    int i = blockIdx.x * 256 + threadIdx.x;
    reinterpret_cast<uint4*>(ws + OFF_HC)[i] = make_uint4(0u, 0u, 0u, 0u);
}

// kernel 2: per-anchor compute (proven R2-R9 math) + LDS hist + replica merge
__global__ __launch_bounds__(512) void dl_main(
    const float* __restrict__ pred_boxes,
    const float* __restrict__ pred_classes,
    const float* __restrict__ true_boxes,
    const int*   __restrict__ true_classes,
    const float* __restrict__ anchors,
    unsigned int* __restrict__ ws)
{
    __shared__ float    s_tb[NOBJ * 4];
    __shared__ int      s_tc[NOBJ];
    __shared__ unsigned lcnt[4096];
    __shared__ float    lsum[4096];
    __shared__ int      s_wi[8][2];
    __shared__ float    s_wf[8][3];

    const int t = threadIdx.x;
    const int idx = blockIdx.x * 512 + t;   // 32 blocks per image; no straddling
    const int b = idx >> 14;
    const int a = idx & (NANCH - 1);
    if (t < NOBJ * 4) s_tb[t] = true_boxes[b * NOBJ * 4 + t];
    if (t < NOBJ)     s_tc[t] = true_classes[b * NOBJ + t];
    for (int i = t; i < 4096; i += 512) { lcnt[i] = 0u; lsum[i] = 0.f; }
    __syncthreads();

    float4 anc = reinterpret_cast<const float4*>(anchors)[a];   // (cx, cy, w, h)
    float ax1 = anc.x - anc.z * 0.5f;
    float ay1 = anc.y - anc.w * 0.5f;
    float ax2 = anc.x + anc.z * 0.5f;
    float ay2 = anc.y + anc.w * 0.5f;
    float area_a = (ax2 - ax1) * (ay2 - ay1);

    float ov[NOBJ];
    float best = -3.402823466e38f;
#pragma unroll
    for (int o = 0; o < NOBJ; ++o) {
        float v;
        if (s_tc[o] < 0) {
            v = -1.0f;   // reference masks padded slots' overlap to -1
        } else {
            float bx1 = s_tb[o * 4 + 0], by1 = s_tb[o * 4 + 1];
            float bx2 = s_tb[o * 4 + 2], by2 = s_tb[o * 4 + 3];
            float ltx = fmaxf(ax1, bx1), lty = fmaxf(ay1, by1);
            float rbx = fminf(ax2, bx2), rby = fminf(ay2, by2);
            float w = fmaxf(rbx - ltx, 0.0f), h = fmaxf(rby - lty, 0.0f);
            float inter = w * h;
            float area_b = (bx2 - bx1) * (by2 - by1);
            v = inter / (area_a + area_b - inter);
        }
        ov[o] = v;
        best = fmaxf(best, v);
    }

    // log-softmax over 2 classes
    float2 pc = reinterpret_cast<const float2*>(pred_classes)[idx];
    float mx = fmaxf(pc.x, pc.y);
    float lse = mx + logf(expf(pc.x - mx) + expf(pc.y - mx));
    float l0 = pc.x - lse;
    float l1 = pc.y - lse;

    // negative: best < 0.5. Histogram nce by exponent + top-4 mantissa bits
    // (sign always 0 for nce >= 0) -> 4096 monotone buckets.
    int isneg = 0;
    if (best < 0.5f) {
        float nce = -l0;
        unsigned bk = (__float_as_uint(nce) >> 19) & 0xFFFu;
        atomicAdd(&lcnt[bk], 1u);
        atomicAdd(&lsum[bk], nce);
        isneg = 1;
    }

    // positives: per o, |best - ov| < 1e-6 and ov > 0.5
    float4 pb = reinterpret_cast<const float4*>(pred_boxes)[idx];
    int npos = 0; float boxs = 0.f, poss = 0.f, wsum = 0.f;
#pragma unroll
    for (int o = 0; o < NOBJ; ++o) {
        float v = ov[o];
        if (fabsf(best - v) < 1e-6f && v > 0.5f) {
            ++npos;
            float bx1 = s_tb[o * 4 + 0], by1 = s_tb[o * 4 + 1];
            float bx2 = s_tb[o * 4 + 2], by2 = s_tb[o * 4 + 3];
            float gcx = ((bx1 + bx2) * 0.5f - anc.x) / (0.1f * anc.z);
            float gcy = ((by1 + by2) * 0.5f - anc.y) / (0.1f * anc.w);
            float gw  = logf((bx2 - bx1) / anc.z) / 0.2f;
            float gh  = logf((by2 - by1) / anc.w) / 0.2f;
            boxs += smooth_l1f(pb.x - gcx) + smooth_l1f(pb.y - gcy)
                  + smooth_l1f(pb.z - gw)  + smooth_l1f(pb.w - gh);
            int c = s_tc[o];
            float w = (c == 1) ? 4.0f : 1.0f;
            poss += w * ((c == 1) ? -l1 : -l0);
            wsum += w;
        }
    }

    // block reduce the 5 stats (8 waves)
    int ip = npos, ng = isneg;
    float fb = boxs, fp = poss, fw = wsum;
#pragma unroll
    for (int o = 32; o; o >>= 1) {
        ip += __shfl_down(ip, o); ng += __shfl_down(ng, o);
        fb += __shfl_down(fb, o); fp += __shfl_down(fp, o); fw += __shfl_down(fw, o);
    }
    const int wave = t >> 6, lane = t & 63;
    if (lane == 0) {
        s_wi[wave][0] = ip; s_wi[wave][1] = ng;
        s_wf[wave][0] = fb; s_wf[wave][1] = fp; s_wf[wave][2] = fw;
    }
    __syncthreads();   // covers LDS hist atomics + s_w* stores
    if (t == 0) {
        int tp = 0, tn = 0; float t2 = 0.f, t3 = 0.f, t4 = 0.f;
        for (int w = 0; w < 8; ++w) {
            tp += s_wi[w][0]; tn += s_wi[w][1];
            t2 += s_wf[w][0]; t3 += s_wf[w][1]; t4 += s_wf[w][2];
        }
        unsigned* sl = ws + OFF_SLOTS + blockIdx.x * 8;
        sl[0] = (unsigned)tp; sl[1] = (unsigned)tn;
        sl[2] = __float_as_uint(t2); sl[3] = __float_as_uint(t3); sl[4] = __float_as_uint(t4);
    }
    // merge nonzero LDS buckets into this block's replica (chains <= MBLK/NREP = 16)
    unsigned* gc = ws + OFF_HC + (blockIdx.x & (NREP - 1)) * 8192;
    float*    gs = reinterpret_cast<float*>(gc + 4096);
    for (int i = t; i < 4096; i += 512) {
        unsigned c = lcnt[i];
        if (c) { atomicAdd(gc + i, c); atomicAdd(gs + i, lsum[i]); }
    }
}

// kernel 3: one block — merge replicas, suffix-scan, cutoff, outputs
__global__ __launch_bounds__(1024) void dl_tail(const unsigned int* __restrict__ ws,
                                                float* __restrict__ out)
{
    __shared__ int   s_wi[16][2];
    __shared__ float s_wf[16][3];
    __shared__ int   wti[16];
    __shared__ float wtf[16];
    __shared__ int   sh_k;
    __shared__ float sh_fp, sh_fw, sh_box, sh_denom;

    const int t = threadIdx.x, wave = t >> 6, lane = t & 63;

    // reduce dl_main slots (256 of them live in waves 0..3)
    int np = 0, nn = 0; float fb = 0.f, fp = 0.f, fw = 0.f;
    if (t < MBLK) {
        const unsigned* sl = ws + OFF_SLOTS + t * 8;
        np = (int)sl[0]; nn = (int)sl[1];
        fb = __uint_as_float(sl[2]); fp = __uint_as_float(sl[3]); fw = __uint_as_float(sl[4]);
    }
#pragma unroll
    for (int o = 32; o; o >>= 1) {
        np += __shfl_down(np, o); nn += __shfl_down(nn, o);
        fb += __shfl_down(fb, o); fp += __shfl_down(fp, o); fw += __shfl_down(fw, o);
    }
    if (lane == 0 && wave < 4) {
        s_wi[wave][0] = np; s_wi[wave][1] = nn;
        s_wf[wave][0] = fb; s_wf[wave][1] = fp; s_wf[wave][2] = fw;
    }
    __syncthreads();
    if (t == 0) {
        int tp = 0, tn = 0; float t2 = 0.f, t3 = 0.f, t4 = 0.f;
        for (int w = 0; w < 4; ++w) {
            tp += s_wi[w][0]; tn += s_wi[w][1];
            t2 += s_wf[w][0]; t3 += s_wf[w][1]; t4 += s_wf[w][2];
        }
        long long k10 = 10LL * (long long)tp;
        int k = (int)((k10 < (long long)tn) ? k10 : (long long)tn);
        sh_k = k;
        sh_fp = t3; sh_fw = t4;
        sh_denom = (float)(tp > 1 ? tp : 1);
        sh_box = t2 / sh_denom;
    }
    __syncthreads();
    const int k = sh_k;
    if (k == 0) {
        if (t == 0) {
            float cls = 10.0f * sh_fp / fmaxf(sh_fw, 1e-6f) / sh_denom;
            out[0] = sh_box; out[1] = cls; out[2] = sh_box + cls;
        }
        return;
    }

    // merge NREP replicas: thread t owns buckets [4t, 4t+4)
    uint4  c4 = make_uint4(0u, 0u, 0u, 0u);
    float4 s4 = make_float4(0.f, 0.f, 0.f, 0.f);
#pragma unroll
    for (int r = 0; r < NREP; ++r) {
        uint4  u = *reinterpret_cast<const uint4*>(ws + OFF_HC + r * 8192 + t * 4);
        float4 s = *reinterpret_cast<const float4*>(ws + OFF_HC + r * 8192 + 4096 + t * 4);
        c4.x += u.x; c4.y += u.y; c4.z += u.z; c4.w += u.w;
        s4.x += s.x; s4.y += s.y; s4.z += s.z; s4.w += s.w;
    }
    unsigned cbk[4] = { c4.x, c4.y, c4.z, c4.w };
    float    sbk[4] = { s4.x, s4.y, s4.z, s4.w };
    int   cc = (int)(cbk[0] + cbk[1] + cbk[2] + cbk[3]);
    float ss = sbk[0] + sbk[1] + sbk[2] + sbk[3];

    // suffix-inclusive scan (count + float sum): wave shuffles + 16 wave totals
    int v = cc; float f = ss;
#pragma unroll
    for (int o = 1; o < 64; o <<= 1) {
        int   u2 = __shfl_down(v, o);
        float g2 = __shfl_down(f, o);
        if (lane + o < 64) { v += u2; f += g2; }
    }
    if (lane == 0) { wti[wave] = v; wtf[wave] = f; }
    __syncthreads();
    int S = v; float FS = f;
    for (int w = wave + 1; w < 16; ++w) { S += wti[w]; FS += wtf[w]; }

    if (S >= k && S - cc < k) {   // exactly one winner thread
        int   cum  = S - cc;      // count in buckets strictly above this thread's 4
        float facc = FS - ss;     // float sum of those buckets (exact)
        float sfx = 0.f;
        for (int bq = 3; bq >= 0; --bq) {
            int cb = (int)cbk[bq];
            if (cum + cb >= k) {
                int r1 = k - cum;     // take r1 of cb from the cut bucket
                float sneg = facc + sfx + (float)r1 * (sbk[bq] / (float)cb);
                float cls = 10.0f * (sh_fp + sneg)
                          / fmaxf(sh_fw + (float)k, 1e-6f) / sh_denom;
                out[0] = sh_box; out[1] = cls; out[2] = sh_box + cls;
                break;
            }
            cum += cb; sfx += sbk[bq];
        }
    }
}

extern "C" void kernel_launch(void* const* d_in, const int* in_sizes, int n_in,
                              void* d_out, int out_size, void* d_ws, size_t ws_size,
                              hipStream_t stream)
{
    const float* pred_boxes   = (const float*)d_in[0];
    const float* pred_classes = (const float*)d_in[1];
    const float* true_boxes   = (const float*)d_in[2];
    const int*   true_classes = (const int*)d_in[3];
    const float* anchors      = (const float*)d_in[4];
    unsigned int* ws = (unsigned int*)d_ws;

    dl_zero<<<128, 256, 0, stream>>>(ws);
    dl_main<<<MBLK, 512, 0, stream>>>(pred_boxes, pred_classes, true_boxes,
                                      true_classes, anchors, ws);
    dl_tail<<<1, 1024, 0, stream>>>(ws, (float*)d_out);
}

// Round 11
// 26.134 us; speedup vs baseline: 2.1071x; 1.1001x over previous
//
#include <hip/hip_runtime.h>
#include <math.h>

#define NOBJ  32
#define NANCH 16384
#define NTOT  131072      // 8 * 16384
#define MBLK  256         // dl_main blocks (512 threads, 1 anchor/thread)
#define NREP  8           // global histogram replicas
#define NBUK  2048        // clamped exponent+4-mantissa-bit buckets
#define BOFF  1792        // bucket offset: (bits>>19) - BOFF, clamped to [0,NBUK)

// ---- ws word layout ----
#define OFF_SLOTS 64                 // 256 blocks * 8 words (np, nn, box, pos, wsum)
#define OFF_HC    2112               // NREP * (cnt[NBUK] + f32 sum[NBUK]) = 32768 words
#define HWORDS    (NREP * NBUK * 2)
// total = OFF_HC + HWORDS = 34880 words ~= 140 KB (ws proven far larger)

__device__ __forceinline__ float smooth_l1f(float d) {
    float ad = fabsf(d);
    return ad < 1.0f ? 0.5f * ad * ad : ad - 0.5f;
}

// kernel 1: zero the histogram replicas (32 blocks * 256 threads * uint4 = 32768 words)
__global__ __launch_bounds__(256) void dl_zero(unsigned int* __restrict__ ws)
{
    int i = blockIdx.x * 256 + threadIdx.x;
    reinterpret_cast<uint4*>(ws + OFF_HC)[i] = make_uint4(0u, 0u, 0u, 0u);
}

// kernel 2: per-anchor compute (proven math) + x2-replicated LDS hist + replica merge
__global__ __launch_bounds__(512) void dl_main(
    const float* __restrict__ pred_boxes,
    const float* __restrict__ pred_classes,
    const float* __restrict__ true_boxes,
    const int*   __restrict__ true_classes,
    const float* __restrict__ anchors,
    unsigned int* __restrict__ ws)
{
    __shared__ float    s_tb[NOBJ * 4];
    __shared__ int      s_tc[NOBJ];
    __shared__ unsigned lcnt[2][NBUK];
    __shared__ float    lsum[2][NBUK];
    __shared__ int      s_wi[8][2];
    __shared__ float    s_wf[8][3];

    const int t = threadIdx.x;
    const int idx = blockIdx.x * 512 + t;   // 32 blocks per image; no straddling
    const int b = idx >> 14;
    const int a = idx & (NANCH - 1);
    if (t < NOBJ * 4) s_tb[t] = true_boxes[b * NOBJ * 4 + t];
    if (t < NOBJ)     s_tc[t] = true_classes[b * NOBJ + t];
    for (int i = t; i < 2 * NBUK; i += 512) { (&lcnt[0][0])[i] = 0u; (&lsum[0][0])[i] = 0.f; }
    __syncthreads();

    float4 anc = reinterpret_cast<const float4*>(anchors)[a];   // (cx, cy, w, h)
    float ax1 = anc.x - anc.z * 0.5f;
    float ay1 = anc.y - anc.w * 0.5f;
    float ax2 = anc.x + anc.z * 0.5f;
    float ay2 = anc.y + anc.w * 0.5f;
    float area_a = (ax2 - ax1) * (ay2 - ay1);

    float ov[NOBJ];
    float best = -3.402823466e38f;
#pragma unroll
    for (int o = 0; o < NOBJ; ++o) {
        float v;
        if (s_tc[o] < 0) {
            v = -1.0f;   // reference masks padded slots' overlap to -1
        } else {
            float bx1 = s_tb[o * 4 + 0], by1 = s_tb[o * 4 + 1];
            float bx2 = s_tb[o * 4 + 2], by2 = s_tb[o * 4 + 3];
            float ltx = fmaxf(ax1, bx1), lty = fmaxf(ay1, by1);
            float rbx = fminf(ax2, bx2), rby = fminf(ay2, by2);
            float w = fmaxf(rbx - ltx, 0.0f), h = fmaxf(rby - lty, 0.0f);
            float inter = w * h;
            float area_b = (bx2 - bx1) * (by2 - by1);
            v = inter / (area_a + area_b - inter);
        }
        ov[o] = v;
        best = fmaxf(best, v);
    }

    // log-softmax over 2 classes
    float2 pc = reinterpret_cast<const float2*>(pred_classes)[idx];
    float mx = fmaxf(pc.x, pc.y);
    float lse = mx + logf(expf(pc.x - mx) + expf(pc.y - mx));
    float l0 = pc.x - lse;
    float l1 = pc.y - lse;

    // negative: best < 0.5. Bucket nce by exponent + top-4 mantissa bits,
    // offset by BOFF and clamped -> NBUK monotone buckets.
    const int wave = t >> 6, lane = t & 63, rep = wave & 1;
    int isneg = 0;
    if (best < 0.5f) {
        float nce = -l0;
        int bk = (int)(__float_as_uint(nce) >> 19) - BOFF;
        bk = bk < 0 ? 0 : (bk > NBUK - 1 ? NBUK - 1 : bk);
        atomicAdd(&lcnt[rep][bk], 1u);
        atomicAdd(&lsum[rep][bk], nce);
        isneg = 1;
    }

    // positives: per o, |best - ov| < 1e-6 and ov > 0.5
    float4 pb = reinterpret_cast<const float4*>(pred_boxes)[idx];
    int npos = 0; float boxs = 0.f, poss = 0.f, wsum = 0.f;
#pragma unroll
    for (int o = 0; o < NOBJ; ++o) {
        float v = ov[o];
        if (fabsf(best - v) < 1e-6f && v > 0.5f) {
            ++npos;
            float bx1 = s_tb[o * 4 + 0], by1 = s_tb[o * 4 + 1];
            float bx2 = s_tb[o * 4 + 2], by2 = s_tb[o * 4 + 3];
            float gcx = ((bx1 + bx2) * 0.5f - anc.x) / (0.1f * anc.z);
            float gcy = ((by1 + by2) * 0.5f - anc.y) / (0.1f * anc.w);
            float gw  = logf((bx2 - bx1) / anc.z) / 0.2f;
            float gh  = logf((by2 - by1) / anc.w) / 0.2f;
            boxs += smooth_l1f(pb.x - gcx) + smooth_l1f(pb.y - gcy)
                  + smooth_l1f(pb.z - gw)  + smooth_l1f(pb.w - gh);
            int c = s_tc[o];
            float w = (c == 1) ? 4.0f : 1.0f;
            poss += w * ((c == 1) ? -l1 : -l0);
            wsum += w;
        }
    }

    // block reduce the 5 stats (8 waves)
    int ip = npos, ng = isneg;
    float fb = boxs, fp = poss, fw = wsum;
#pragma unroll
    for (int o = 32; o; o >>= 1) {
        ip += __shfl_down(ip, o); ng += __shfl_down(ng, o);
        fb += __shfl_down(fb, o); fp += __shfl_down(fp, o); fw += __shfl_down(fw, o);
    }
    if (lane == 0) {
        s_wi[wave][0] = ip; s_wi[wave][1] = ng;
        s_wf[wave][0] = fb; s_wf[wave][1] = fp; s_wf[wave][2] = fw;
    }
    __syncthreads();   // covers LDS hist atomics + s_w* stores
    if (t == 0) {
        int tp = 0, tn = 0; float t2 = 0.f, t3 = 0.f, t4 = 0.f;
        for (int w = 0; w < 8; ++w) {
            tp += s_wi[w][0]; tn += s_wi[w][1];
            t2 += s_wf[w][0]; t3 += s_wf[w][1]; t4 += s_wf[w][2];
        }
        unsigned* sl = ws + OFF_SLOTS + blockIdx.x * 8;
        sl[0] = (unsigned)tp; sl[1] = (unsigned)tn;
        sl[2] = __float_as_uint(t2); sl[3] = __float_as_uint(t3); sl[4] = __float_as_uint(t4);
    }
    // merge nonzero buckets into this block's replica (chains <= MBLK/NREP = 32)
    unsigned* gc = ws + OFF_HC + (blockIdx.x & (NREP - 1)) * (NBUK * 2);
    float*    gs = reinterpret_cast<float*>(gc + NBUK);
    for (int i = t; i < NBUK; i += 512) {
        unsigned c = lcnt[0][i] + lcnt[1][i];
        if (c) { atomicAdd(gc + i, c); atomicAdd(gs + i, lsum[0][i] + lsum[1][i]); }
    }
}

// kernel 3: one block — merge replicas, suffix-scan, cutoff, outputs
__global__ __launch_bounds__(1024) void dl_tail(const unsigned int* __restrict__ ws,
                                                float* __restrict__ out)
{
    __shared__ int   s_wi[16][2];
    __shared__ float s_wf[16][3];
    __shared__ int   wti[16];
    __shared__ float wtf[16];
    __shared__ int   sh_k;
    __shared__ float sh_fp, sh_fw, sh_box, sh_denom;

    const int t = threadIdx.x, wave = t >> 6, lane = t & 63;

    // reduce dl_main slots (256 of them live in waves 0..3)
    int np = 0, nn = 0; float fb = 0.f, fp = 0.f, fw = 0.f;
    if (t < MBLK) {
        const unsigned* sl = ws + OFF_SLOTS + t * 8;
        np = (int)sl[0]; nn = (int)sl[1];
        fb = __uint_as_float(sl[2]); fp = __uint_as_float(sl[3]); fw = __uint_as_float(sl[4]);
    }
#pragma unroll
    for (int o = 32; o; o >>= 1) {
        np += __shfl_down(np, o); nn += __shfl_down(nn, o);
        fb += __shfl_down(fb, o); fp += __shfl_down(fp, o); fw += __shfl_down(fw, o);
    }
    if (lane == 0 && wave < 4) {
        s_wi[wave][0] = np; s_wi[wave][1] = nn;
        s_wf[wave][0] = fb; s_wf[wave][1] = fp; s_wf[wave][2] = fw;
    }
    __syncthreads();
    if (t == 0) {
        int tp = 0, tn = 0; float t2 = 0.f, t3 = 0.f, t4 = 0.f;
        for (int w = 0; w < 4; ++w) {
            tp += s_wi[w][0]; tn += s_wi[w][1];
            t2 += s_wf[w][0]; t3 += s_wf[w][1]; t4 += s_wf[w][2];
        }
        long long k10 = 10LL * (long long)tp;
        int k = (int)((k10 < (long long)tn) ? k10 : (long long)tn);
        sh_k = k;
        sh_fp = t3; sh_fw = t4;
        sh_denom = (float)(tp > 1 ? tp : 1);
        sh_box = t2 / sh_denom;
    }
    __syncthreads();
    const int k = sh_k;
    if (k == 0) {
        if (t == 0) {
            float cls = 10.0f * sh_fp / fmaxf(sh_fw, 1e-6f) / sh_denom;
            out[0] = sh_box; out[1] = cls; out[2] = sh_box + cls;
        }
        return;
    }

    // merge NREP replicas: thread t owns buckets [2t, 2t+2)
    unsigned cbk[2] = {0u, 0u};
    float    sbk[2] = {0.f, 0.f};
#pragma unroll
    for (int r = 0; r < NREP; ++r) {
        uint2  u = *reinterpret_cast<const uint2*>(ws + OFF_HC + r * (NBUK * 2) + t * 2);
        float2 s = *reinterpret_cast<const float2*>(ws + OFF_HC + r * (NBUK * 2) + NBUK + t * 2);
        cbk[0] += u.x; cbk[1] += u.y;
        sbk[0] += s.x; sbk[1] += s.y;
    }
    int   cc = (int)(cbk[0] + cbk[1]);
    float ss = sbk[0] + sbk[1];

    // suffix-inclusive scan (count + float sum): wave shuffles + 16 wave totals
    int v = cc; float f = ss;
#pragma unroll
    for (int o = 1; o < 64; o <<= 1) {
        int   u2 = __shfl_down(v, o);
        float g2 = __shfl_down(f, o);
        if (lane + o < 64) { v += u2; f += g2; }
    }
    if (lane == 0) { wti[wave] = v; wtf[wave] = f; }
    __syncthreads();
    int S = v; float FS = f;
    for (int w = wave + 1; w < 16; ++w) { S += wti[w]; FS += wtf[w]; }

    if (S >= k && S - cc < k) {   // exactly one winner thread
        int   cum  = S - cc;      // count in buckets strictly above this thread's 2
        float facc = FS - ss;     // float sum of those buckets (exact)
        float sfx = 0.f;
        for (int bq = 1; bq >= 0; --bq) {
            int cb = (int)cbk[bq];
            if (cum + cb >= k) {
                int r1 = k - cum;     // take r1 of cb from the cut bucket (mean approx)
                float sneg = facc + sfx + (float)r1 * (sbk[bq] / (float)cb);
                float cls = 10.0f * (sh_fp + sneg)
                          / fmaxf(sh_fw + (float)k, 1e-6f) / sh_denom;
                out[0] = sh_box; out[1] = cls; out[2] = sh_box + cls;
                break;
            }
            cum += cb; sfx += sbk[bq];
        }
    }
}

extern "C" void kernel_launch(void* const* d_in, const int* in_sizes, int n_in,
                              void* d_out, int out_size, void* d_ws, size_t ws_size,
                              hipStream_t stream)
{
    const float* pred_boxes   = (const float*)d_in[0];
    const float* pred_classes = (const float*)d_in[1];
    const float* true_boxes   = (const float*)d_in[2];
    const int*   true_classes = (const int*)d_in[3];
    const float* anchors      = (const float*)d_in[4];
    unsigned int* ws = (unsigned int*)d_ws;

    dl_zero<<<32, 256, 0, stream>>>(ws);
    dl_main<<<MBLK, 512, 0, stream>>>(pred_boxes, pred_classes, true_boxes,
                                      true_classes, anchors, ws);
    dl_tail<<<1, 1024, 0, stream>>>(ws, (float*)d_out);
}